// Round 1
// baseline (2313.750 us; speedup 1.0000x reference)
//
#include <hip/hip_runtime.h>

// Problem constants
#define NL 24
#define NB 4
#define NS 2048
#define NS1 2049
#define ND 512
#define NH 16
#define DH 32
#define DFF 2048
#define CCH 128      // attention chunk rows
#define NCHUNK 17    // 16 chunks of 128 + 1 new-token chunk
#define LN_EPS 1e-5f

__device__ __forceinline__ float dot4(float4 a, float4 b) {
    return a.x * b.x + a.y * b.y + a.z * b.z + a.w * b.w;
}

__device__ __forceinline__ float wsum(float v) {
#pragma unroll
    for (int m = 1; m < 64; m <<= 1) v += __shfl_xor(v, m);
    return v;
}

__device__ __forceinline__ float wmax(float v) {
#pragma unroll
    for (int m = 1; m < 64; m <<= 1) v = fmaxf(v, __shfl_xor(v, m));
    return v;
}

// ---------------------------------------------------------------------------
// QKV: x_l = (layer==0 ? x_in : LN2(x1_prev + t_prev)); qkv = x_l @ qkv_w^T + b
// Writes q to ws, new-token k/v to d_out cache position S, and x_l to ws.xcur.
// grid (96, NB), block 256. Each wave computes 4 output rows (wave-reduced dot).
// ---------------------------------------------------------------------------
__global__ __launch_bounds__(256) void qkv_kernel(
    const float* __restrict__ x_in,
    const float* __restrict__ x1b, const float* __restrict__ tb,
    const float* __restrict__ l2w, const float* __restrict__ l2b,  // offset to layer-1
    const float* __restrict__ qkvw, const float* __restrict__ qkvb,
    float* __restrict__ qbuf, float* __restrict__ xcur,
    float* __restrict__ ko, float* __restrict__ vo, int layer)
{
    const int chunkI = blockIdx.x, b = blockIdx.y;
    const int t = threadIdx.x;
    __shared__ float xl[ND];
    __shared__ float r1s[4], r2s[4];

    if (layer == 0) {
        xl[t] = x_in[b * ND + t];
        xl[256 + t] = x_in[b * ND + 256 + t];
    } else {
        const float u0 = x1b[b * ND + t] + tb[b * ND + t];
        const float u1 = x1b[b * ND + 256 + t] + tb[b * ND + 256 + t];
        float s1 = u0 + u1, s2 = u0 * u0 + u1 * u1;
        s1 = wsum(s1); s2 = wsum(s2);
        if ((t & 63) == 0) { r1s[t >> 6] = s1; r2s[t >> 6] = s2; }
        __syncthreads();
        const float mean = (r1s[0] + r1s[1] + r1s[2] + r1s[3]) * (1.f / ND);
        const float var = (r2s[0] + r2s[1] + r2s[2] + r2s[3]) * (1.f / ND) - mean * mean;
        const float inv = rsqrtf(var + LN_EPS);
        xl[t] = (u0 - mean) * inv * l2w[t] + l2b[t];
        xl[256 + t] = (u1 - mean) * inv * l2w[256 + t] + l2b[256 + t];
    }
    __syncthreads();
    if (chunkI == 0) {  // materialize x_l for the out-proj residual
        xcur[b * ND + t] = xl[t];
        xcur[b * ND + 256 + t] = xl[256 + t];
    }
    const int wv = t >> 6, lane = t & 63;
    const float4 xa = *(const float4*)&xl[lane * 4];
    const float4 xb = *(const float4*)&xl[256 + lane * 4];
#pragma unroll
    for (int k = 0; k < 4; ++k) {
        const int row = chunkI * 16 + wv * 4 + k;
        const float* wr = qkvw + ((size_t)layer * 1536 + row) * ND;
        const float4 wa = *(const float4*)(wr + lane * 4);
        const float4 wb = *(const float4*)(wr + 256 + lane * 4);
        float p = dot4(xa, wa) + dot4(xb, wb);
        p = wsum(p);
        if (lane == 0) {
            p += qkvb[layer * 1536 + row];
            if (row < ND) {
                qbuf[b * ND + row] = p;
            } else if (row < 2 * ND) {
                ko[(((size_t)layer * NB + b) * NS1 + NS) * ND + (row - ND)] = p;
            } else {
                vo[(((size_t)layer * NB + b) * NS1 + NS) * ND + (row - 2 * ND)] = p;
            }
        }
    }
}

// ---------------------------------------------------------------------------
// Fused flash-decode attention chunk + KV cache copy.
// grid (NCHUNK, NH, NB), block 256.  chunk<16: 128 rows read from input cache,
// copied to d_out, scores+partial softmax+partial PV.  chunk 16: the new token
// (read back from d_out, written by qkv_kernel).
// ---------------------------------------------------------------------------
__global__ __launch_bounds__(256) void attn_kernel(
    const float* __restrict__ kc, const float* __restrict__ vc,
    float* __restrict__ ko, float* __restrict__ vo,
    const float* __restrict__ qbuf,
    float* __restrict__ opart, float* __restrict__ mbuf, float* __restrict__ lbuf,
    int layer)
{
    const int chunk = blockIdx.x, h = blockIdx.y, b = blockIdx.z;
    const int t = threadIdx.x, sl = t >> 3, c = t & 7;
    __shared__ float sc[CCH];
    __shared__ float redm[4], reds[4];
    __shared__ float ow[4][8][4];

    const float scale = 0.17677669529663687f;  // 1/sqrt(32)
    const float4 q4 = *(const float4*)(qbuf + (size_t)b * ND + h * DH + c * 4);
    float4 vv0 = {0, 0, 0, 0}, vv1 = {0, 0, 0, 0}, vv2 = {0, 0, 0, 0}, vv3 = {0, 0, 0, 0};
    int nsc;
    if (chunk < 16) {
        nsc = CCH;
        const int s0 = chunk * CCH;
#pragma unroll
        for (int p = 0; p < 4; ++p) {
            const int s = s0 + p * 32 + sl;
            const size_t src = (((size_t)layer * NB + b) * NS + s) * ND + h * DH + c * 4;
            const size_t dst = (((size_t)layer * NB + b) * NS1 + s) * ND + h * DH + c * 4;
            const float4 k4 = *(const float4*)(kc + src);
            const float4 v4 = *(const float4*)(vc + src);
            *(float4*)(ko + dst) = k4;   // fused cache copy
            *(float4*)(vo + dst) = v4;
            if (p == 0) vv0 = v4; else if (p == 1) vv1 = v4; else if (p == 2) vv2 = v4; else vv3 = v4;
            float pr = dot4(q4, k4);
            pr += __shfl_xor(pr, 1); pr += __shfl_xor(pr, 2); pr += __shfl_xor(pr, 4);
            if (c == 0) sc[p * 32 + sl] = pr * scale;
        }
    } else {
        nsc = 1;
        if (sl == 0) {
            const size_t dst = (((size_t)layer * NB + b) * NS1 + NS) * ND + h * DH + c * 4;
            const float4 k4 = *(const float4*)(ko + dst);
            vv0 = *(const float4*)(vo + dst);
            float pr = dot4(q4, k4);
            pr += __shfl_xor(pr, 1); pr += __shfl_xor(pr, 2); pr += __shfl_xor(pr, 4);
            if (c == 0) sc[0] = pr * scale;
        }
    }
    __syncthreads();
    // block max
    float lm = -1e30f;
    for (int i = t; i < nsc; i += 256) lm = fmaxf(lm, sc[i]);
    lm = wmax(lm);
    if ((t & 63) == 0) redm[t >> 6] = lm;
    __syncthreads();
    const float mg = fmaxf(fmaxf(redm[0], redm[1]), fmaxf(redm[2], redm[3]));
    // exp + block sum
    float ls = 0.f;
    for (int i = t; i < nsc; i += 256) { const float p = __expf(sc[i] - mg); sc[i] = p; ls += p; }
    ls = wsum(ls);
    if ((t & 63) == 0) reds[t >> 6] = ls;
    __syncthreads();
    const float lg = reds[0] + reds[1] + reds[2] + reds[3];
    // partial PV
    float4 acc = {0, 0, 0, 0};
    if (chunk < 16) {
        const float w0 = sc[0 * 32 + sl], w1 = sc[1 * 32 + sl], w2 = sc[2 * 32 + sl], w3 = sc[3 * 32 + sl];
        acc.x = w0 * vv0.x + w1 * vv1.x + w2 * vv2.x + w3 * vv3.x;
        acc.y = w0 * vv0.y + w1 * vv1.y + w2 * vv2.y + w3 * vv3.y;
        acc.z = w0 * vv0.z + w1 * vv1.z + w2 * vv2.z + w3 * vv3.z;
        acc.w = w0 * vv0.w + w1 * vv1.w + w2 * vv2.w + w3 * vv3.w;
    } else if (sl == 0) {
        const float w0 = sc[0];
        acc.x = w0 * vv0.x; acc.y = w0 * vv0.y; acc.z = w0 * vv0.z; acc.w = w0 * vv0.w;
    }
#pragma unroll
    for (int m = 8; m < 64; m <<= 1) {
        acc.x += __shfl_xor(acc.x, m); acc.y += __shfl_xor(acc.y, m);
        acc.z += __shfl_xor(acc.z, m); acc.w += __shfl_xor(acc.w, m);
    }
    const int wv = t >> 6, lane = t & 63;
    if (lane < 8) { ow[wv][lane][0] = acc.x; ow[wv][lane][1] = acc.y; ow[wv][lane][2] = acc.z; ow[wv][lane][3] = acc.w; }
    __syncthreads();
    if (t < 8) {
        float4 o4;
        o4.x = ow[0][t][0] + ow[1][t][0] + ow[2][t][0] + ow[3][t][0];
        o4.y = ow[0][t][1] + ow[1][t][1] + ow[2][t][1] + ow[3][t][1];
        o4.z = ow[0][t][2] + ow[1][t][2] + ow[2][t][2] + ow[3][t][2];
        o4.w = ow[0][t][3] + ow[1][t][3] + ow[2][t][3] + ow[3][t][3];
        *(float4*)(opart + ((size_t)(b * NH + h) * NCHUNK + chunk) * DH + t * 4) = o4;
    }
    if (t == 0) { mbuf[(b * NH + h) * NCHUNK + chunk] = mg; lbuf[(b * NH + h) * NCHUNK + chunk] = lg; }
}

// ---------------------------------------------------------------------------
// Finalize attention (combine chunk partials, redundant per block) + out-proj
// + residual.  grid (16, NB), block 256; each wave computes 8 output rows.
// ---------------------------------------------------------------------------
__global__ __launch_bounds__(256) void outproj_kernel(
    const float* __restrict__ opart, const float* __restrict__ mbuf, const float* __restrict__ lbuf,
    const float* __restrict__ outw, const float* __restrict__ outb,
    const float* __restrict__ xcur, float* __restrict__ r1b, int layer)
{
    const int chunkI = blockIdx.x, b = blockIdx.y;
    const int t = threadIdx.x;
    __shared__ float ofin[ND];
    __shared__ float wgt[NH][NCHUNK + 1];
    if (t < NH) {
        const int h = t;
        const float* mp = mbuf + (b * NH + h) * NCHUNK;
        const float* lp = lbuf + (b * NH + h) * NCHUNK;
        float mgl = -1e30f;
        for (int k = 0; k < NCHUNK; ++k) mgl = fmaxf(mgl, mp[k]);
        float lg = 0.f;
        for (int k = 0; k < NCHUNK; ++k) lg += lp[k] * __expf(mp[k] - mgl);
        const float invl = 1.f / lg;
        for (int k = 0; k < NCHUNK; ++k) wgt[h][k] = __expf(mp[k] - mgl) * invl;
    }
    __syncthreads();
    for (int i = t; i < ND; i += 256) {
        const int h = i >> 5, d = i & 31;
        const float* op = opart + (size_t)(b * NH + h) * NCHUNK * DH + d;
        float a = 0.f;
        for (int k = 0; k < NCHUNK; ++k) a += wgt[h][k] * op[k * DH];
        ofin[i] = a;
    }
    __syncthreads();
    const int wv = t >> 6, lane = t & 63;
    const float4 oa = *(const float4*)&ofin[lane * 4];
    const float4 ob = *(const float4*)&ofin[256 + lane * 4];
#pragma unroll
    for (int k = 0; k < 8; ++k) {
        const int i = chunkI * 32 + wv * 8 + k;
        const float* wr = outw + ((size_t)layer * ND + i) * ND;
        const float4 wa = *(const float4*)(wr + lane * 4);
        const float4 wb = *(const float4*)(wr + 256 + lane * 4);
        float p = dot4(oa, wa) + dot4(ob, wb);
        p = wsum(p);
        if (lane == 0) r1b[b * ND + i] = xcur[b * ND + i] + p + outb[layer * ND + i];
    }
}

// ---------------------------------------------------------------------------
// FFN1: x1 = LN1(r1) (redundant per block, materialized by chunk 0);
// h = relu(x1 @ w1^T + b1).  grid (64, NB), block 256; 8 rows/wave.
// ---------------------------------------------------------------------------
__global__ __launch_bounds__(256) void ffn1_kernel(
    const float* __restrict__ r1b, const float* __restrict__ l1w, const float* __restrict__ l1b,
    const float* __restrict__ w1, const float* __restrict__ b1,
    float* __restrict__ x1b, float* __restrict__ hb, int layer)
{
    const int chunkI = blockIdx.x, b = blockIdx.y;
    const int t = threadIdx.x;
    __shared__ float xl[ND];
    __shared__ float r1s[4], r2s[4];
    const float u0 = r1b[b * ND + t], u1 = r1b[b * ND + 256 + t];
    float s1 = u0 + u1, s2 = u0 * u0 + u1 * u1;
    s1 = wsum(s1); s2 = wsum(s2);
    if ((t & 63) == 0) { r1s[t >> 6] = s1; r2s[t >> 6] = s2; }
    __syncthreads();
    const float mean = (r1s[0] + r1s[1] + r1s[2] + r1s[3]) * (1.f / ND);
    const float var = (r2s[0] + r2s[1] + r2s[2] + r2s[3]) * (1.f / ND) - mean * mean;
    const float inv = rsqrtf(var + LN_EPS);
    const float v0 = (u0 - mean) * inv * l1w[layer * ND + t] + l1b[layer * ND + t];
    const float v1 = (u1 - mean) * inv * l1w[layer * ND + 256 + t] + l1b[layer * ND + 256 + t];
    xl[t] = v0; xl[256 + t] = v1;
    if (chunkI == 0) { x1b[b * ND + t] = v0; x1b[b * ND + 256 + t] = v1; }
    __syncthreads();
    const int wv = t >> 6, lane = t & 63;
    const float4 xa = *(const float4*)&xl[lane * 4];
    const float4 xb = *(const float4*)&xl[256 + lane * 4];
#pragma unroll
    for (int k = 0; k < 8; ++k) {
        const int row = chunkI * 32 + wv * 8 + k;
        const float* wr = w1 + ((size_t)layer * DFF + row) * ND;
        const float4 wa = *(const float4*)(wr + lane * 4);
        const float4 wb = *(const float4*)(wr + 256 + lane * 4);
        float p = dot4(xa, wa) + dot4(xb, wb);
        p = wsum(p);
        if (lane == 0) hb[b * DFF + row] = fmaxf(p + b1[(size_t)layer * DFF + row], 0.f);
    }
}

// ---------------------------------------------------------------------------
// FFN2: t = h @ w2^T + b2.  grid (64, NB), block 256; 2 rows/wave (K=2048).
// ---------------------------------------------------------------------------
__global__ __launch_bounds__(256) void ffn2_kernel(
    const float* __restrict__ hb, const float* __restrict__ w2, const float* __restrict__ b2,
    float* __restrict__ tb, int layer)
{
    const int chunkI = blockIdx.x, b = blockIdx.y;
    const int t = threadIdx.x;
    __shared__ float hl[DFF];
    for (int i = t; i < DFF; i += 256) hl[i] = hb[b * DFF + i];
    __syncthreads();
    const int wv = t >> 6, lane = t & 63;
    float4 ha[8];
#pragma unroll
    for (int j = 0; j < 8; ++j) ha[j] = *(const float4*)&hl[j * 256 + lane * 4];
#pragma unroll
    for (int k = 0; k < 2; ++k) {
        const int i = chunkI * 8 + wv * 2 + k;
        const float* wr = w2 + ((size_t)layer * ND + i) * DFF;
        float p = 0.f;
#pragma unroll
        for (int j = 0; j < 8; ++j) {
            const float4 w4 = *(const float4*)(wr + j * 256 + lane * 4);
            p += dot4(ha[j], w4);
        }
        p = wsum(p);
        if (lane == 0) tb[b * ND + i] = p + b2[layer * ND + i];
    }
}

// ---------------------------------------------------------------------------
// Final LN2 of last layer -> x_out.  grid NB, block 256.
// ---------------------------------------------------------------------------
__global__ __launch_bounds__(256) void final_kernel(
    const float* __restrict__ x1b, const float* __restrict__ tb,
    const float* __restrict__ l2w, const float* __restrict__ l2b,  // offset to layer 23
    float* __restrict__ xout)
{
    const int b = blockIdx.x, t = threadIdx.x;
    __shared__ float r1s[4], r2s[4];
    const float u0 = x1b[b * ND + t] + tb[b * ND + t];
    const float u1 = x1b[b * ND + 256 + t] + tb[b * ND + 256 + t];
    float s1 = u0 + u1, s2 = u0 * u0 + u1 * u1;
    s1 = wsum(s1); s2 = wsum(s2);
    if ((t & 63) == 0) { r1s[t >> 6] = s1; r2s[t >> 6] = s2; }
    __syncthreads();
    const float mean = (r1s[0] + r1s[1] + r1s[2] + r1s[3]) * (1.f / ND);
    const float var = (r2s[0] + r2s[1] + r2s[2] + r2s[3]) * (1.f / ND) - mean * mean;
    const float inv = rsqrtf(var + LN_EPS);
    xout[b * ND + t] = (u0 - mean) * inv * l2w[t] + l2b[t];
    xout[b * ND + 256 + t] = (u1 - mean) * inv * l2w[256 + t] + l2b[256 + t];
}

// ---------------------------------------------------------------------------
extern "C" void kernel_launch(void* const* d_in, const int* in_sizes, int n_in,
                              void* d_out, int out_size, void* d_ws, size_t ws_size,
                              hipStream_t stream)
{
    (void)in_sizes; (void)n_in; (void)out_size; (void)ws_size;
    const float* x      = (const float*)d_in[0];
    const float* kcache = (const float*)d_in[1];
    const float* vcache = (const float*)d_in[2];
    const float* qkvw   = (const float*)d_in[3];
    const float* qkvb   = (const float*)d_in[4];
    const float* outw   = (const float*)d_in[5];
    const float* outb   = (const float*)d_in[6];
    const float* w1     = (const float*)d_in[7];
    const float* b1     = (const float*)d_in[8];
    const float* w2     = (const float*)d_in[9];
    const float* b2     = (const float*)d_in[10];
    const float* l1w    = (const float*)d_in[11];
    const float* l1b    = (const float*)d_in[12];
    const float* l2w    = (const float*)d_in[13];
    const float* l2b    = (const float*)d_in[14];

    float* out  = (float*)d_out;
    float* xout = out;                                  // [4,1,512]
    float* ko   = out + NB * ND;                        // [24,4,2049,512]
    float* vo   = ko + (size_t)NL * NB * NS1 * ND;      // [24,4,2049,512]

    float* ws    = (float*)d_ws;
    float* qbuf  = ws;            // 2048
    float* xcur  = ws + 2048;     // 2048
    float* r1b   = ws + 4096;     // 2048
    float* x1b   = ws + 6144;     // 2048
    float* tb    = ws + 8192;     // 2048
    float* hb    = ws + 10240;    // 8192
    float* opart = ws + 18432;    // 4*16*17*32 = 34816
    float* mbuf  = ws + 53248;    // 1088
    float* lbuf  = ws + 54336;    // 1088

    for (int l = 0; l < NL; ++l) {
        const int lp = (l > 0) ? (l - 1) : 0;
        qkv_kernel<<<dim3(96, NB), 256, 0, stream>>>(
            x, x1b, tb, l2w + (size_t)lp * ND, l2b + (size_t)lp * ND,
            qkvw, qkvb, qbuf, xcur, ko, vo, l);
        attn_kernel<<<dim3(NCHUNK, NH, NB), 256, 0, stream>>>(
            kcache, vcache, ko, vo, qbuf, opart, mbuf, lbuf, l);
        outproj_kernel<<<dim3(16, NB), 256, 0, stream>>>(
            opart, mbuf, lbuf, outw, outb, xcur, r1b, l);
        ffn1_kernel<<<dim3(64, NB), 256, 0, stream>>>(
            r1b, l1w, l1b, w1, b1, x1b, hb, l);
        ffn2_kernel<<<dim3(64, NB), 256, 0, stream>>>(
            hb, w2, b2, tb, l);
    }
    final_kernel<<<NB, 256, 0, stream>>>(
        x1b, tb, l2w + (size_t)23 * ND, l2b + (size_t)23 * ND, xout);
}